// Round 1
// 16512.390 us; speedup vs baseline: 1.2026x; 1.2026x over previous
//
#include <hip/hip_runtime.h>

typedef __bf16 bf16x8 __attribute__((ext_vector_type(8)));
typedef float f32x4 __attribute__((ext_vector_type(4)));
typedef unsigned short u16;
typedef unsigned int u32;
typedef unsigned long long u64;

#define MFMA16(a, b, c) __builtin_amdgcn_mfma_f32_16x16x32_bf16((a), (b), (c), 0, 0, 0)

namespace {
constexpr int kB = 32, kS = 2048, kI = 128, kH = 512, kO = 128;
constexpr int NC = 2;      // independent batch clusters of 16
constexpr int BPC = 16;    // batches per cluster (== MFMA M)
constexpr int L0WG = 16;   // layer-0 WGs per cluster (32 cols each)
constexpr int WGC = 48;    // + 32 layer-1 WGs (16 cols each)
constexpr int NSLOT = 4;   // publish-slot rotation depth (poison protocol)
constexpr int NT = 2 * kS + 3;
constexpr long LOUT = (long)kB * kS * kO;
constexpr u32 POISON = 0xFFFFFFFFu;  // 2x bf16 NaN; finite data never packs to this

// workspace byte offsets
constexpr size_t WS_FLG  = 0;                                 // [NC][48] flags, 64B stride
constexpr size_t WS_PUB0 = 8192;                              // [NC][4][16][512] bf16
constexpr size_t BUFSZ   = (size_t)NC * NSLOT * BPC * kH * 2; // 131072 B per buffer
constexpr size_t WS_PUB1 = WS_PUB0 + BUFSZ;
constexpr size_t WS_PR0  = WS_PUB1 + BUFSZ;
constexpr size_t WS_PR1  = WS_PR0 + BUFSZ;
constexpr size_t WS_WTS  = WS_PR1 + BUFSZ;

// weight element offsets (u16) within WS_WTS
constexpr int W0H = 0;        // [3][512][512]  (z,r,g)
constexpr int W0X = 786432;   // [3][512][128]
constexpr int W1X = 983040;   // [3][512][512]
constexpr int W1H = 1769472;  // [3][512][512]
constexpr int WYO = 2555904;  // [128][512]

constexpr int CSLOT = BPC * kH;       // 8192 u16 per slot
constexpr int CBUF  = NSLOT * CSLOT;  // 32768 u16 per cluster
}

__device__ __forceinline__ u16 f2bf(float f) {
  u32 x = __float_as_uint(f);
  return (u16)((x + 0x7fffu + ((x >> 16) & 1u)) >> 16);  // RNE
}

__device__ __forceinline__ u64 ld64a(const u64* p) {
  return __hip_atomic_load((u64*)p, __ATOMIC_RELAXED, __HIP_MEMORY_SCOPE_AGENT);
}
__device__ __forceinline__ u32 ld32a(const u32* p) {
  return __hip_atomic_load((u32*)p, __ATOMIC_RELAXED, __HIP_MEMORY_SCOPE_AGENT);
}
__device__ __forceinline__ bool bad(u64 v) {
  return ((u32)v == POISON) | ((u32)(v >> 32) == POISON);
}

// 8 MFMA A-fragments (16B each) loaded straight from the coherent publish slot.
// issue(): batch-issue all 16 u64 loads (guaranteed MLP). get(s): validate with
// per-u32 poison check, retrying only stale words.
struct Frags {
  u64 v[16];
  const u64* p;
  __device__ __forceinline__ void issue(const u16* base) {
    p = (const u64*)base;
#pragma unroll
    for (int s = 0; s < 8; ++s) {
      v[2 * s]     = ld64a(p + s * 8);
      v[2 * s + 1] = ld64a(p + s * 8 + 1);
    }
  }
  __device__ __forceinline__ bf16x8 get(int s) {
    u64 a = v[2 * s], b = v[2 * s + 1];
    while (bad(a)) a = ld64a(p + s * 8);
    while (bad(b)) b = ld64a(p + s * 8 + 1);
    union { u64 d[2]; bf16x8 f; } u_;
    u_.d[0] = a; u_.d[1] = b;
    return u_.f;
  }
};

__device__ __forceinline__ bf16x8 pack8(float4 a, float4 b) {
  union { u16 s[8]; bf16x8 v; } u_;
  u_.s[0] = f2bf(a.x); u_.s[1] = f2bf(a.y); u_.s[2] = f2bf(a.z); u_.s[3] = f2bf(a.w);
  u_.s[4] = f2bf(b.x); u_.s[5] = f2bf(b.y); u_.s[6] = f2bf(b.z); u_.s[7] = f2bf(b.w);
  return u_.v;
}

// ---------------- prep: fp32 -> bf16 weights, init slots & poison & flags ----
__global__ void prep_kernel(const float* whz0, const float* whr0, const float* whg0,
                            const float* wxz0, const float* wxr0, const float* wxg0,
                            const float* wxz1, const float* wxr1, const float* wxg1,
                            const float* whz1, const float* whr1, const float* whg1,
                            const float* wy, const float* h0in, char* ws) {
  u16* wts = (u16*)(ws + WS_WTS);
  int gid = blockIdx.x * blockDim.x + threadIdx.x;
  int stride = gridDim.x * blockDim.x;
  for (int i = gid; i < 786432; i += stride) {
    int g = i >> 18, r = i & 262143;
    wts[W0H + i] = f2bf((g == 0 ? whz0 : g == 1 ? whr0 : whg0)[r]);
  }
  for (int i = gid; i < 196608; i += stride) {
    int g = i >> 16, r = i & 65535;
    wts[W0X + i] = f2bf((g == 0 ? wxz0 : g == 1 ? wxr0 : wxg0)[r]);
  }
  for (int i = gid; i < 786432; i += stride) {
    int g = i >> 18, r = i & 262143;
    wts[W1X + i] = f2bf((g == 0 ? wxz1 : g == 1 ? wxr1 : wxg1)[r]);
  }
  for (int i = gid; i < 786432; i += stride) {
    int g = i >> 18, r = i & 262143;
    wts[W1H + i] = f2bf((g == 0 ? whz1 : g == 1 ? whr1 : whg1)[r]);
  }
  for (int i = gid; i < 65536; i += stride) wts[WYO + i] = f2bf(wy[i]);

  // poison pr0/pr1 (all 4 slots) and pub0/pub1 (slots 0..2); slot 3 gets h0
  u32* r0 = (u32*)(ws + WS_PR0);
  u32* r1 = (u32*)(ws + WS_PR1);
  u32* b0 = (u32*)(ws + WS_PUB0);
  u32* b1 = (u32*)(ws + WS_PUB1);
  constexpr int NW = (int)(BUFSZ / 4);  // 32768 u32 per buffer
  for (int i = gid; i < NW; i += stride) { r0[i] = POISON; r1[i] = POISON; }
  for (int i = gid; i < NW; i += stride) {
    int s = (i >> 12) & 3;  // [c][s][4096 u32]
    if (s != 3) { b0[i] = POISON; b1[i] = POISON; }
  }
  u16* p0 = (u16*)(ws + WS_PUB0);
  u16* p1 = (u16*)(ws + WS_PUB1);
  for (int i = gid; i < NC * BPC * kH; i += stride) {
    int c = i / (BPC * kH), rem = i - c * (BPC * kH);
    int b = rem / kH, k = rem - b * kH;
    int bg = c * BPC + b;
    p0[c * CBUF + 3 * CSLOT + rem] = f2bf(h0in[(size_t)bg * 2 * kH + k]);
    p1[c * CBUF + 3 * CSLOT + rem] = f2bf(h0in[(size_t)bg * 2 * kH + kH + k]);
  }
  if (gid < 2048) ((u32*)(ws + WS_FLG))[gid] = 0u;
}

// ---------------- helpers ----------------
__device__ __forceinline__ void st_tile(float* base, f32x4 c, int q, int li) {
  // C/D layout: D[row=q*4+r][col=li]; row = batch. Stride 17 spreads banks.
#pragma unroll
  for (int r = 0; r < 4; ++r) base[(q * 4 + r) * 17 + li] = c[r];
}

// publish 2 adjacent bf16 columns as one coherent u32 store
__device__ __forceinline__ void pub2(u16* base, int off, float v0, float v1) {
  u32 pk = (u32)f2bf(v0) | ((u32)f2bf(v1) << 16);
  __hip_atomic_store((u32*)(base + off), pk, __ATOMIC_RELAXED, __HIP_MEMORY_SCOPE_AGENT);
}
__device__ __forceinline__ void poison2(u16* base, int off) {
  __hip_atomic_store((u32*)(base + off), POISON, __ATOMIC_RELAXED, __HIP_MEMORY_SCOPE_AGENT);
}

__device__ __forceinline__ float sigm(float x) { return 1.f / (1.f + __expf(-x)); }
__device__ __forceinline__ float tanh_f(float x) {
  float te = __expf(-2.f * fabsf(x));
  return __builtin_copysignf((1.f - te) / (1.f + te), x);
}

// ---------------- persistent pipelined GRU ----------------
// Protocol: publishes rotate through 4 slots; producer at step t writes slot t%4
// and re-poisons slot (t+2)%4. Consumers poll the data words directly (u32
// validity). A lazy per-tick gate (all flags >= tk-2, checked only before the
// store phase) bounds skew to 2 ticks, which makes every poison/overwrite safe.
__global__ __launch_bounds__(256, 1)
void gru_kernel(const float* __restrict__ xg, const float* __restrict__ h0in,
                const float* __restrict__ bxz0, const float* __restrict__ bxr0,
                const float* __restrict__ bxg0, const float* __restrict__ bxz1,
                const float* __restrict__ bxr1, const float* __restrict__ bxg1,
                const float* __restrict__ byv, float* __restrict__ out, char* ws) {
  const int cl = blockIdx.x / WGC;
  const int wid = blockIdx.x - cl * WGC;
  const bool isL0 = wid < L0WG;
  const int w0 = wid, w1 = wid - L0WG;
  const int tid = threadIdx.x;
  const int lane = tid & 63, wv = tid >> 6;
  const int q = lane >> 4, li = lane & 15;
  const int kh = wv & 1;      // K-half this wave owns
  const int nt = wv >> 1;     // L0: which 16-col tile of the WG's 32 cols
  const bool xside = wv < 2;  // L1 role split

  u16* pub0 = (u16*)(ws + WS_PUB0) + (size_t)cl * CBUF;
  u16* pub1 = (u16*)(ws + WS_PUB1) + (size_t)cl * CBUF;
  u16* pr0  = (u16*)(ws + WS_PR0)  + (size_t)cl * CBUF;
  u16* pr1  = (u16*)(ws + WS_PR1)  + (size_t)cl * CBUF;
  const u16* wts = (const u16*)(ws + WS_WTS);
  u32* flags = (u32*)(ws + WS_FLG) + (size_t)cl * 1024;

  __shared__ __align__(16) float smem[5984];
  float* spA = smem;            // even-tick partials (20 x 272 f32)
  float* spB = smem;            // odd-tick partials (alias)
  float* ypA = smem + 5440;     // y partials [2kh][272]

  // ---- persistent register-resident weight fragments ----
  bf16x8 wA[3][8];  // L0: Wh0 z/r/g | L1 x-waves: W1x z/r/g | L1 h-waves: W1h z/r/g
  bf16x8 wE[8];     // L0: Wx0 z/r/g packed [g*2+s] | L1 h-waves w1<8: wy
  if (isL0) {
    const int ci = w0 * 32 + nt * 16 + li;
#pragma unroll
    for (int g = 0; g < 3; ++g)
#pragma unroll
      for (int s = 0; s < 8; ++s)
        wA[g][s] = *(const bf16x8*)(wts + W0H + ((size_t)(g * kH + ci) * kH + kh * 256 + q * 8 + s * 32));
#pragma unroll
    for (int g = 0; g < 3; ++g)
#pragma unroll
      for (int s = 0; s < 2; ++s)
        wE[g * 2 + s] = *(const bf16x8*)(wts + W0X + ((size_t)(g * kH + ci) * kI + kh * 64 + q * 8 + s * 32));
  } else {
    const int ci = w1 * 16 + li;
    const int base = xside ? W1X : W1H;
#pragma unroll
    for (int g = 0; g < 3; ++g)
#pragma unroll
      for (int s = 0; s < 8; ++s)
        wA[g][s] = *(const bf16x8*)(wts + base + ((size_t)(g * kH + ci) * kH + kh * 256 + q * 8 + s * 32));
    if (!xside && w1 < 8) {
#pragma unroll
      for (int s = 0; s < 8; ++s)
        wE[s] = *(const bf16x8*)(wts + WYO + ((size_t)ci * kH + kh * 256 + q * 8 + s * 32));
    }
  }

  // ---- per-thread biases + f32 master state + phase A->B stash ----
  float2 bz2 = {0.f, 0.f}, br2 = {0.f, 0.f}, bg2 = {0.f, 0.f};
  float by_r = 0.f;
  float hm0r = 0.f, hm1r = 0.f;
  float zA0 = 0.f, zA1 = 0.f, gA0 = 0.f, gA1 = 0.f;
  if (isL0) {
    const int c0i = (tid & 15) * 2, bq = tid >> 4;
    bz2 = *(const float2*)(bxz0 + w0 * 32 + c0i);
    br2 = *(const float2*)(bxr0 + w0 * 32 + c0i);
    bg2 = *(const float2*)(bxg0 + w0 * 32 + c0i);
    const float* hp = h0in + (size_t)(cl * 16 + bq) * 2 * kH + w0 * 32 + c0i;
    hm0r = hp[0]; hm1r = hp[1];
  } else {
    const int c0i = (tid & 7) * 2, bq = tid >> 3;
    bz2 = *(const float2*)(bxz1 + w1 * 16 + c0i);
    br2 = *(const float2*)(bxr1 + w1 * 16 + c0i);
    bg2 = *(const float2*)(bxg1 + w1 * 16 + c0i);
    if (bq < 16) {
      const float* hp = h0in + (size_t)(cl * 16 + bq) * 2 * kH + kH + w1 * 16 + c0i;
      hm0r = hp[0]; hm1r = hp[1];
    }
    if (w1 < 8) by_r = byv[w1 * 16 + (tid & 15)];
  }

  for (int tk = 0; tk < NT; ++tk) {
    const bool ev = (tk & 1) == 0;
    const int t = tk >> 1;  // L0 step (phase A at 2t, B at 2t+1)
    const int u = t - 1;    // L1 step
    const bool l0A = isL0 && ev && t < kS;
    const bool l0B = isL0 && !ev && t < kS;
    const bool l1A = !isL0 && ev && t >= 1 && t <= kS;
    const bool l1B = !isL0 && !ev && t >= 1 && t <= kS;
    const bool yAct = !isL0 && ev && w1 < 8 && t >= 2 && t <= kS + 1;

    // early flag snapshot; enforced only before the store phase
    u32 myfl = 0xFFFFFFFFu;
    if (lane < WGC) myfl = ld32a(flags + lane * 16);
    const u32 need = (tk >= 2) ? (u32)(tk - 2) : 0u;

    // ---- MFMA with direct poll-validated fragment loads ----
    if (l0A) {
      Frags F;
      F.issue(pub0 + ((t + 3) & 3) * CSLOT + li * kH + kh * 256 + q * 8);
      const float* xr = xg + ((size_t)(cl * 16 + li) * kS + t) * kI + kh * 64 + q * 8;
      float4 xv0 = *(const float4*)xr;
      float4 xv1 = *(const float4*)(xr + 4);
      float4 xv2 = *(const float4*)(xr + 32);
      float4 xv3 = *(const float4*)(xr + 36);
      f32x4 hz = {0.f, 0.f, 0.f, 0.f}, hr = hz, xz = hz, xr2 = hz, xg2 = hz;
#pragma unroll
      for (int s = 0; s < 8; ++s) {
        bf16x8 a = F.get(s);
        hz = MFMA16(a, wA[0][s], hz);
        hr = MFMA16(a, wA[1][s], hr);
      }
      {
        bf16x8 a = pack8(xv0, xv1);
        xz  = MFMA16(a, wE[0], xz);
        xr2 = MFMA16(a, wE[2], xr2);
        xg2 = MFMA16(a, wE[4], xg2);
      }
      {
        bf16x8 a = pack8(xv2, xv3);
        xz  = MFMA16(a, wE[1], xz);
        xr2 = MFMA16(a, wE[3], xr2);
        xg2 = MFMA16(a, wE[5], xg2);
      }
      st_tile(spA + ((0 * 2 + nt) * 2 + kh) * 272, hz, q, li);
      st_tile(spA + ((1 * 2 + nt) * 2 + kh) * 272, hr, q, li);
      st_tile(spA + ((2 * 2 + nt) * 2 + kh) * 272, xz, q, li);
      st_tile(spA + ((3 * 2 + nt) * 2 + kh) * 272, xr2, q, li);
      st_tile(spA + ((4 * 2 + nt) * 2 + kh) * 272, xg2, q, li);
    } else if (!isL0 && ev) {
      if (xside) {
        if (l1A) {  // x-side of layer 1: input is h0(u)
          Frags F;
          F.issue(pub0 + (u & 3) * CSLOT + li * kH + kh * 256 + q * 8);
          f32x4 cz = {0.f, 0.f, 0.f, 0.f}, cr = cz, cg = cz;
#pragma unroll
          for (int s = 0; s < 8; ++s) {
            bf16x8 a = F.get(s);
            cz = MFMA16(a, wA[0][s], cz);
            cr = MFMA16(a, wA[1][s], cr);
            cg = MFMA16(a, wA[2][s], cg);
          }
          st_tile(spA + (2 * 2 + kh) * 272, cz, q, li);
          st_tile(spA + (3 * 2 + kh) * 272, cr, q, li);
          st_tile(spA + (4 * 2 + kh) * 272, cg, q, li);
        }
      } else {
        const bool rec = t >= 1 && t <= kS;
        const bool ym = (w1 < 8) && t >= 2 && t <= kS + 1;
        if (rec || ym) {  // h-side z,r of layer 1 + y, both consume h1(u-1)
          Frags F;
          F.issue(pub1 + ((t + 2) & 3) * CSLOT + li * kH + kh * 256 + q * 8);
          f32x4 cz = {0.f, 0.f, 0.f, 0.f}, cr = cz, cy = cz;
#pragma unroll
          for (int s = 0; s < 8; ++s) {
            bf16x8 a = F.get(s);
            if (rec) {
              cz = MFMA16(a, wA[0][s], cz);
              cr = MFMA16(a, wA[1][s], cr);
            }
            if (ym) cy = MFMA16(a, wE[s], cy);
          }
          if (rec) {
            st_tile(spA + (0 * 2 + kh) * 272, cz, q, li);
            st_tile(spA + (1 * 2 + kh) * 272, cr, q, li);
          }
          if (ym) st_tile(ypA + kh * 272, cy, q, li);
        }
      }
    } else if (l0B) {
      Frags F;
      F.issue(pr0 + (t & 3) * CSLOT + li * kH + kh * 256 + q * 8);
      f32x4 cg = {0.f, 0.f, 0.f, 0.f};
#pragma unroll
      for (int s = 0; s < 8; ++s) cg = MFMA16(F.get(s), wA[2][s], cg);
      st_tile(spB + (nt * 2 + kh) * 272, cg, q, li);
    } else if (l1B && !xside) {
      Frags F;
      F.issue(pr1 + (u & 3) * CSLOT + li * kH + kh * 256 + q * 8);
      f32x4 cg = {0.f, 0.f, 0.f, 0.f};
#pragma unroll
      for (int s = 0; s < 8; ++s) cg = MFMA16(F.get(s), wA[2][s], cg);
      st_tile(spB + kh * 272, cg, q, li);
    }
    __syncthreads();

    // gate: bound skew to 2 ticks before any publish/poison store
    while (__any((int)(myfl < need))) {
      if (lane < WGC) myfl = ld32a(flags + lane * 16);
    }

    // ---- activations / publish (+poison of slot t+2) ----
    if (l0A) {
      const int cp = tid & 15, b = tid >> 4;
      const int c0 = cp * 2, n2 = c0 >> 4, cc = c0 & 15, o = b * 17 + cc;
      float hz0 = spA[((0*2+n2)*2+0)*272 + o] + spA[((0*2+n2)*2+1)*272 + o];
      float hz1 = spA[((0*2+n2)*2+0)*272 + o+1] + spA[((0*2+n2)*2+1)*272 + o+1];
      float hr0 = spA[((1*2+n2)*2+0)*272 + o] + spA[((1*2+n2)*2+1)*272 + o];
      float hr1 = spA[((1*2+n2)*2+0)*272 + o+1] + spA[((1*2+n2)*2+1)*272 + o+1];
      float xz0 = spA[((2*2+n2)*2+0)*272 + o] + spA[((2*2+n2)*2+1)*272 + o];
      float xz1 = spA[((2*2+n2)*2+0)*272 + o+1] + spA[((2*2+n2)*2+1)*272 + o+1];
      float xr0 = spA[((3*2+n2)*2+0)*272 + o] + spA[((3*2+n2)*2+1)*272 + o];
      float xr1 = spA[((3*2+n2)*2+0)*272 + o+1] + spA[((3*2+n2)*2+1)*272 + o+1];
      float xg0 = spA[((4*2+n2)*2+0)*272 + o] + spA[((4*2+n2)*2+1)*272 + o];
      float xg1 = spA[((4*2+n2)*2+0)*272 + o+1] + spA[((4*2+n2)*2+1)*272 + o+1];
      zA0 = sigm(hz0 + xz0 + bz2.x);
      zA1 = sigm(hz1 + xz1 + bz2.y);
      float r0v = sigm(hr0 + xr0 + br2.x);
      float r1v = sigm(hr1 + xr1 + br2.y);
      gA0 = xg0 + bg2.x;
      gA1 = xg1 + bg2.y;
      const int off = b * kH + w0 * 32 + c0;
      pub2(pr0 + (t & 3) * CSLOT, off, r0v * hm0r, r1v * hm1r);
      poison2(pr0 + ((t + 2) & 3) * CSLOT, off);
    }
    if (l1A && tid < 128) {
      const int cp = tid & 7, b = tid >> 3;
      const int c0 = cp * 2, o = b * 17 + c0;
      float hz0 = spA[(0*2+0)*272 + o] + spA[(0*2+1)*272 + o];
      float hz1 = spA[(0*2+0)*272 + o+1] + spA[(0*2+1)*272 + o+1];
      float hr0 = spA[(1*2+0)*272 + o] + spA[(1*2+1)*272 + o];
      float hr1 = spA[(1*2+0)*272 + o+1] + spA[(1*2+1)*272 + o+1];
      float xz0 = spA[(2*2+0)*272 + o] + spA[(2*2+1)*272 + o];
      float xz1 = spA[(2*2+0)*272 + o+1] + spA[(2*2+1)*272 + o+1];
      float xr0 = spA[(3*2+0)*272 + o] + spA[(3*2+1)*272 + o];
      float xr1 = spA[(3*2+0)*272 + o+1] + spA[(3*2+1)*272 + o+1];
      float xg0 = spA[(4*2+0)*272 + o] + spA[(4*2+1)*272 + o];
      float xg1 = spA[(4*2+0)*272 + o+1] + spA[(4*2+1)*272 + o+1];
      zA0 = sigm(hz0 + xz0 + bz2.x);
      zA1 = sigm(hz1 + xz1 + bz2.y);
      float r0v = sigm(hr0 + xr0 + br2.x);
      float r1v = sigm(hr1 + xr1 + br2.y);
      gA0 = xg0 + bg2.x;
      gA1 = xg1 + bg2.y;
      const int off = b * kH + w1 * 16 + c0;
      pub2(pr1 + (u & 3) * CSLOT, off, r0v * hm0r, r1v * hm1r);
      poison2(pr1 + ((u + 2) & 3) * CSLOT, off);
    }
    if (yAct) {
      const int c = tid & 15, b = tid >> 4;
      float y = ypA[b * 17 + c] + ypA[272 + b * 17 + c] + by_r;
      out[((size_t)(cl * 16 + b) * kS + (t - 2)) * kO + w1 * 16 + c] = y;
    }
    if (l0B) {
      const int cp = tid & 15, b = tid >> 4;
      const int c0 = cp * 2, n2 = c0 >> 4, cc = c0 & 15, o = b * 17 + cc;
      float gh0 = spB[(n2*2+0)*272 + o] + spB[(n2*2+1)*272 + o];
      float gh1 = spB[(n2*2+0)*272 + o+1] + spB[(n2*2+1)*272 + o+1];
      float g0 = tanh_f(gA0 + gh0), g1 = tanh_f(gA1 + gh1);
      float hn0 = zA0 * hm0r + (1.f - zA0) * g0;
      float hn1 = zA1 * hm1r + (1.f - zA1) * g1;
      hm0r = hn0; hm1r = hn1;
      const int off = b * kH + w0 * 32 + c0;
      pub2(pub0 + (t & 3) * CSLOT, off, hn0, hn1);
      poison2(pub0 + ((t + 2) & 3) * CSLOT, off);
      if (t == kS - 1) {
        float* op = out + LOUT + (size_t)(cl * 16 + b) * 2 * kH + w0 * 32 + c0;
        op[0] = hn0; op[1] = hn1;
      }
    }
    if (l1B && tid < 128) {
      const int cp = tid & 7, b = tid >> 3;
      const int c0 = cp * 2, o = b * 17 + c0;
      float gh0 = spB[0 * 272 + o] + spB[1 * 272 + o];
      float gh1 = spB[0 * 272 + o+1] + spB[1 * 272 + o+1];
      float g0 = tanh_f(gA0 + gh0), g1 = tanh_f(gA1 + gh1);
      float hn0 = zA0 * hm0r + (1.f - zA0) * g0;
      float hn1 = zA1 * hm1r + (1.f - zA1) * g1;
      hm0r = hn0; hm1r = hn1;
      const int off = b * kH + w1 * 16 + c0;
      pub2(pub1 + (u & 3) * CSLOT, off, hn0, hn1);
      poison2(pub1 + ((u + 2) & 3) * CSLOT, off);
      if (u == kS - 1) {
        float* op = out + LOUT + (size_t)(cl * 16 + b) * 2 * kH + kH + w1 * 16 + c0;
        op[0] = hn0; op[1] = hn1;
      }
    }

    // drain all publishes (syncthreads waits vmcnt per wave), then arrive
    __syncthreads();
    if (tid == 0 && tk != NT - 1)
      __hip_atomic_store(flags + wid * 16, (u32)(tk + 1), __ATOMIC_RELAXED,
                         __HIP_MEMORY_SCOPE_AGENT);
  }
}

extern "C" void kernel_launch(void* const* d_in, const int* in_sizes, int n_in,
                              void* d_out, int out_size, void* d_ws, size_t ws_size,
                              hipStream_t stream) {
  (void)in_sizes; (void)n_in; (void)out_size; (void)ws_size;
  const float* x      = (const float*)d_in[0];
  const float* h0     = (const float*)d_in[1];
  const float* l0_wxz = (const float*)d_in[2];
  const float* l0_bxz = (const float*)d_in[3];
  const float* l0_whz = (const float*)d_in[4];
  const float* l0_wxr = (const float*)d_in[5];
  const float* l0_bxr = (const float*)d_in[6];
  const float* l0_whr = (const float*)d_in[7];
  const float* l0_wxg = (const float*)d_in[8];
  const float* l0_bxg = (const float*)d_in[9];
  const float* l0_whg = (const float*)d_in[10];
  const float* l1_wxz = (const float*)d_in[11];
  const float* l1_bxz = (const float*)d_in[12];
  const float* l1_whz = (const float*)d_in[13];
  const float* l1_wxr = (const float*)d_in[14];
  const float* l1_bxr = (const float*)d_in[15];
  const float* l1_whr = (const float*)d_in[16];
  const float* l1_wxg = (const float*)d_in[17];
  const float* l1_bxg = (const float*)d_in[18];
  const float* l1_whg = (const float*)d_in[19];
  const float* wy     = (const float*)d_in[20];
  const float* by     = (const float*)d_in[21];
  float* out = (float*)d_out;
  char* ws = (char*)d_ws;

  prep_kernel<<<512, 256, 0, stream>>>(l0_whz, l0_whr, l0_whg, l0_wxz, l0_wxr, l0_wxg,
                                       l1_wxz, l1_wxr, l1_wxg, l1_whz, l1_whr, l1_whg,
                                       wy, h0, ws);
  gru_kernel<<<NC * WGC, 256, 0, stream>>>(x, h0, l0_bxz, l0_bxr, l0_bxg,
                                           l1_bxz, l1_bxr, l1_bxg, by, out, ws);
}